// Round 1
// baseline (560.757 us; speedup 1.0000x reference)
//
#include <hip/hip_runtime.h>
#include <stdint.h>

#define M_DIM 8192
#define K_DIM 4096
#define N_DIM 4096
#define KTILES (K_DIM / 64)

typedef __attribute__((ext_vector_type(4))) int i32x4;

// ---------------------------------------------------------------------------
// Pack int32-stored int8 weights [N,K] -> true int8 [N,K]; also per-row sum
// folded into integer correction corr[n] = (128 - zp) * rowsum[n].
// ---------------------------------------------------------------------------
__global__ void pack_w_kernel(const int* __restrict__ w, char* __restrict__ wp,
                              int* __restrict__ corr, const int* __restrict__ zpp) {
  __shared__ int red[256];
  const int n = blockIdx.x;
  const int t = threadIdx.x;
  const int4* row = (const int4*)(w + (size_t)n * K_DIM);
  int s = 0;
  int words[4];
#pragma unroll
  for (int u = 0; u < 4; ++u) {
    int4 v = row[t * 4 + u];
    s += v.x + v.y + v.z + v.w;
    words[u] = (v.x & 255) | ((v.y & 255) << 8) | ((v.z & 255) << 16) | (v.w << 24);
  }
  ((int4*)(wp + (size_t)n * K_DIM))[t] = make_int4(words[0], words[1], words[2], words[3]);
  red[t] = s;
  __syncthreads();
  for (int off = 128; off > 0; off >>= 1) {
    if (t < off) red[t] += red[t + off];
    __syncthreads();
  }
  if (t == 0) corr[n] = (128 - zpp[0]) * red[0];
}

// ---------------------------------------------------------------------------
// Quantize fp32 input -> int8 (q - 128), 4 elements/thread.
// ---------------------------------------------------------------------------
__global__ void quant_in_kernel(const float* __restrict__ x, char* __restrict__ q,
                                const float* __restrict__ sp, const int* __restrict__ zpp) {
  const int i = blockIdx.x * blockDim.x + threadIdx.x;
  const float s = sp[0];
  const float zp = (float)zpp[0];
  float4 v = ((const float4*)x)[i];
  float t0 = fminf(fmaxf(rintf(v.x / s) + zp, 0.f), 255.f);
  float t1 = fminf(fmaxf(rintf(v.y / s) + zp, 0.f), 255.f);
  float t2 = fminf(fmaxf(rintf(v.z / s) + zp, 0.f), 255.f);
  float t3 = fminf(fmaxf(rintf(v.w / s) + zp, 0.f), 255.f);
  int b0 = (int)t0 - 128, b1 = (int)t1 - 128, b2 = (int)t2 - 128, b3 = (int)t3 - 128;
  ((int*)q)[i] = (b0 & 255) | ((b1 & 255) << 8) | ((b2 & 255) << 16) | (b3 << 24);
}

// ---------------------------------------------------------------------------
// int8 GEMM: out[m,n] = fscale[n]*(idot(m,n)+corr[n]) + bias[n]
// A = qa [M,K] int8 (activations, already q-128), B = wb [N,K] int8.
// Tile 128x128, BK=64, 256 threads = 4 waves (2x2), each wave 64x64 out
// = 4x4 fragments of v_mfma_i32_16x16x64_i8.
// WRITE_Q=1: epilogue re-quantizes to int8 (next layer input).
// WRITE_Q=0: epilogue writes fp32.
// LDS XOR swizzle: physical 16B-slot g_phys = g ^ ((row>>1)&3); applied to the
// *global source* address at staging (global_load_lds writes linearly) and to
// the ds_read address (same involution) -> conflict-free b128 reads.
// ---------------------------------------------------------------------------
template <int WRITE_Q>
__global__ __launch_bounds__(256) void gemm_kernel(
    const char* __restrict__ qa, const char* __restrict__ wb,
    const int* __restrict__ corr, const float* __restrict__ swp,
    const float* __restrict__ bias, const float* __restrict__ sp,
    const int* __restrict__ zpp, char* __restrict__ outq, float* __restrict__ outf) {
  __shared__ __align__(16) char lds[2][2][128 * 64];
  const int tid = threadIdx.x;
  const int lane = tid & 63;
  const int w = tid >> 6;
  const int wr = w >> 1;
  const int wc = w & 1;
  const int bid = blockIdx.x;
  const int bm = bid & 63;  // M/128 = 64, fastest-varying: neighbors share B panel
  const int bn = bid >> 6;  // N/128 = 32
  const char* abase = qa + (size_t)bm * 128 * K_DIM;
  const char* bbase = wb + (size_t)bn * 128 * K_DIM;

  i32x4 acc[4][4] = {};

  auto stage = [&](int kt, int buf) {
#pragma unroll
    for (int c = 0; c < 2; ++c) {
      int o = c * 4096 + tid * 16;
      int r = o >> 6;                          // tile row this 16B lands in
      int g = ((o >> 4) & 3) ^ ((r >> 1) & 3); // inverse-swizzled source slot
      size_t goff = (size_t)r * K_DIM + kt * 64 + g * 16;
      __builtin_amdgcn_global_load_lds(
          (const __attribute__((address_space(1))) void*)(abase + goff),
          (__attribute__((address_space(3))) void*)(&lds[buf][0][c * 4096 + (w << 10)]),
          16, 0, 0);
      __builtin_amdgcn_global_load_lds(
          (const __attribute__((address_space(1))) void*)(bbase + goff),
          (__attribute__((address_space(3))) void*)(&lds[buf][1][c * 4096 + (w << 10)]),
          16, 0, 0);
    }
  };

  stage(0, 0);
  for (int kt = 0; kt < KTILES; ++kt) {
    const int cur = kt & 1;
    __syncthreads();  // drains vmcnt: staging of buf[cur] complete, all waves
    if (kt + 1 < KTILES) stage(kt + 1, cur ^ 1);
    const int g = lane >> 4;
    const int rr = lane & 15;
    i32x4 af[4], bf[4];
#pragma unroll
    for (int i = 0; i < 4; ++i) {
      int row = wr * 64 + i * 16 + rr;
      int gp = g ^ ((row >> 1) & 3);
      af[i] = *(const i32x4*)(&lds[cur][0][row * 64 + gp * 16]);
    }
#pragma unroll
    for (int j = 0; j < 4; ++j) {
      int row = wc * 64 + j * 16 + rr;
      int gp = g ^ ((row >> 1) & 3);
      bf[j] = *(const i32x4*)(&lds[cur][1][row * 64 + gp * 16]);
    }
#pragma unroll
    for (int i = 0; i < 4; ++i)
#pragma unroll
      for (int j = 0; j < 4; ++j)
        acc[i][j] = __builtin_amdgcn_mfma_i32_16x16x64_i8(af[i], bf[j], acc[i][j], 0, 0, 0);
  }

  // epilogue: C/D layout col = lane&15 (n), row = (lane>>4)*4 + reg (m)
  const float s = sp[0];
  const float zpf = (float)zpp[0];
  const int m0 = bm * 128 + wr * 64 + (lane >> 4) * 4;
  const int n0 = bn * 128 + wc * 64 + (lane & 15);
#pragma unroll
  for (int j = 0; j < 4; ++j) {
    const int n = n0 + j * 16;
    const int cr = corr[n];
    const float fs = s * swp[n];
    const float bb = bias[n];
#pragma unroll
    for (int i = 0; i < 4; ++i) {
      const int mbase = m0 + i * 16;
#pragma unroll
      for (int q = 0; q < 4; ++q) {
        const int m = mbase + q;
        float val = fs * (float)(acc[i][j][q] + cr) + bb;
        if (WRITE_Q) {
          float t = fminf(fmaxf(rintf(val / s) + zpf, 0.f), 255.f);
          outq[(size_t)m * N_DIM + n] = (char)((int)t - 128);
        } else {
          outf[(size_t)m * N_DIM + n] = val;
        }
      }
    }
  }
}

// ---------------------------------------------------------------------------
extern "C" void kernel_launch(void* const* d_in, const int* in_sizes, int n_in,
                              void* d_out, int out_size, void* d_ws, size_t ws_size,
                              hipStream_t stream) {
  const float* x = (const float*)d_in[0];
  const int* wq = (const int*)d_in[1];
  const float* bias = (const float*)d_in[2];
  const float* s_in = (const float*)d_in[3];
  const int* zp_in = (const int*)d_in[4];
  const float* s_w = (const float*)d_in[5];
  float* out = (float*)d_out;

  // workspace layout
  const size_t WP_BYTES = (size_t)N_DIM * K_DIM;       // 16 MB packed int8 W
  const size_t Q_BYTES = (size_t)M_DIM * K_DIM;        // 32 MB int8 activations
  char* ws = (char*)d_ws;
  char* wp = ws;
  char* q1 = ws + WP_BYTES;
  char* q2 = q1 + Q_BYTES;
  int* corr = (int*)(q2 + Q_BYTES);
  const size_t NEEDED = WP_BYTES + 2 * Q_BYTES + (size_t)N_DIM * sizeof(int);
  if (ws_size < NEEDED) return;  // cannot run without scratch

  pack_w_kernel<<<N_DIM, 256, 0, stream>>>(wq, wp, corr, zp_in);
  quant_in_kernel<<<(M_DIM * K_DIM / 4) / 256, 256, 0, stream>>>(x, q1, s_in, zp_in);

  dim3 grid((M_DIM / 128) * (N_DIM / 128));  // 2048 blocks
  dim3 blk(256);
  gemm_kernel<1><<<grid, blk, 0, stream>>>(q1, wp, corr, s_w, bias, s_in, zp_in, q2, nullptr);
  gemm_kernel<1><<<grid, blk, 0, stream>>>(q2, wp, corr, s_w, bias, s_in, zp_in, q1, nullptr);
  gemm_kernel<0><<<grid, blk, 0, stream>>>(q1, wp, corr, s_w, bias, s_in, zp_in, nullptr, out);
}

// Round 2
// 458.720 us; speedup vs baseline: 1.2224x; 1.2224x over previous
//
#include <hip/hip_runtime.h>
#include <stdint.h>

#define M_DIM 8192
#define K_DIM 4096
#define N_DIM 4096
#define KTILES (K_DIM / 64)

typedef __attribute__((ext_vector_type(4))) int i32x4;

// ---------------------------------------------------------------------------
// Pack int32-stored int8 weights [N,K] -> true int8 [N,K]; per-row sum folded
// into integer correction corr[n] = (128 - zp) * rowsum[n].
// ---------------------------------------------------------------------------
__global__ void pack_w_kernel(const int* __restrict__ w, char* __restrict__ wp,
                              int* __restrict__ corr, const int* __restrict__ zpp) {
  __shared__ int red[256];
  const int n = blockIdx.x;
  const int t = threadIdx.x;
  const int4* row = (const int4*)(w + (size_t)n * K_DIM);
  int s = 0;
  int words[4];
#pragma unroll
  for (int u = 0; u < 4; ++u) {
    int4 v = row[t * 4 + u];
    s += v.x + v.y + v.z + v.w;
    words[u] = (v.x & 255) | ((v.y & 255) << 8) | ((v.z & 255) << 16) | (v.w << 24);
  }
  ((int4*)(wp + (size_t)n * K_DIM))[t] = make_int4(words[0], words[1], words[2], words[3]);
  red[t] = s;
  __syncthreads();
  for (int off = 128; off > 0; off >>= 1) {
    if (t < off) red[t] += red[t + off];
    __syncthreads();
  }
  if (t == 0) corr[n] = (128 - zpp[0]) * red[0];
}

// ---------------------------------------------------------------------------
// Quantize fp32 input -> int8 (q - 128), 4 elements/thread.
// ---------------------------------------------------------------------------
__global__ void quant_in_kernel(const float* __restrict__ x, char* __restrict__ q,
                                const float* __restrict__ sp, const int* __restrict__ zpp) {
  const int i = blockIdx.x * blockDim.x + threadIdx.x;
  const float s = sp[0];
  const float zp = (float)zpp[0];
  float4 v = ((const float4*)x)[i];
  float t0 = fminf(fmaxf(rintf(v.x / s) + zp, 0.f), 255.f);
  float t1 = fminf(fmaxf(rintf(v.y / s) + zp, 0.f), 255.f);
  float t2 = fminf(fmaxf(rintf(v.z / s) + zp, 0.f), 255.f);
  float t3 = fminf(fmaxf(rintf(v.w / s) + zp, 0.f), 255.f);
  int b0 = (int)t0 - 128, b1 = (int)t1 - 128, b2 = (int)t2 - 128, b3 = (int)t3 - 128;
  ((int*)q)[i] = (b0 & 255) | ((b1 & 255) << 8) | ((b2 & 255) << 16) | (b3 << 24);
}

// ---------------------------------------------------------------------------
// 256x256 8-phase-style i8 GEMM (T2+T3+T4+T5).
// A = qa [M,K] int8 (q-128), B = wb [N,K] int8, out = fs[n]*(dot+corr[n])+b[n].
// 512 threads = 8 waves (2M x 4N), per-wave 128x64 out, BK=64 bytes.
// LDS: 4-slot ring of K-tiles (A 16KB + B 16KB each) = 128 KB, prefetch
// distance 3. Per K-tile 2 phases; counted vmcnt(8) once per tile.
// Swizzle: 16B slot g_phys = g ^ ((row>>1)&3), applied to global source at
// staging (global_load_lds writes linearly) and to ds_read addr (same
// involution) -> 2-way-max bank aliasing (free). Verified 0 conflicts in R1.
// ---------------------------------------------------------------------------
#define VM8 asm volatile("s_waitcnt vmcnt(8)" ::: "memory")
#define VM4 asm volatile("s_waitcnt vmcnt(4)" ::: "memory")
#define VM0 asm volatile("s_waitcnt vmcnt(0)" ::: "memory")
#define VMN ((void)0)

#define GEMM_TILE(T, DO_STAGE, VM_A)                                                   \
  {                                                                                    \
    const int buf_ = (T) & 3;                                                          \
    const int nslot_ = ((T) + 3) & 3;                                                  \
    char* bufA_ = &lds[buf_][0][0];                                                    \
    char* bufB_ = &lds[buf_][1][0];                                                    \
    i32x4 af[4], bf[4];                                                                \
    _Pragma("unroll") for (int i = 0; i < 4; ++i)                                      \
        af[i] = *(const i32x4*)(bufA_ + aoff[i]);                                      \
    _Pragma("unroll") for (int j = 0; j < 4; ++j)                                      \
        bf[j] = *(const i32x4*)(bufB_ + boff[j]);                                      \
    if (DO_STAGE) {                                                                    \
      STAGE16(asrc0 + (size_t)((T) + 3) * 64, &lds[nslot_][0][o0_]);                   \
      STAGE16(asrc1 + (size_t)((T) + 3) * 64, &lds[nslot_][0][o1_]);                   \
    }                                                                                  \
    __builtin_amdgcn_s_barrier();                                                      \
    asm volatile("s_waitcnt lgkmcnt(0)" ::: "memory");                                 \
    __builtin_amdgcn_s_setprio(1);                                                     \
    _Pragma("unroll") for (int i = 0; i < 4; ++i)                                      \
        _Pragma("unroll") for (int j = 0; j < 4; ++j)                                  \
            acc[i][j] = __builtin_amdgcn_mfma_i32_16x16x64_i8(af[i], bf[j], acc[i][j], 0, 0, 0); \
    __builtin_amdgcn_s_setprio(0);                                                     \
    __builtin_amdgcn_s_barrier();                                                      \
    i32x4 af2[4];                                                                      \
    _Pragma("unroll") for (int i = 0; i < 4; ++i)                                      \
        af2[i] = *(const i32x4*)(bufA_ + aoff[4 + i]);                                 \
    if (DO_STAGE) {                                                                    \
      STAGE16(bsrc0 + (size_t)((T) + 3) * 64, &lds[nslot_][1][o0_]);                   \
      STAGE16(bsrc1 + (size_t)((T) + 3) * 64, &lds[nslot_][1][o1_]);                   \
    }                                                                                  \
    VM_A;                                                                              \
    __builtin_amdgcn_s_barrier();                                                      \
    asm volatile("s_waitcnt lgkmcnt(0)" ::: "memory");                                 \
    __builtin_amdgcn_s_setprio(1);                                                     \
    _Pragma("unroll") for (int i = 0; i < 4; ++i)                                      \
        _Pragma("unroll") for (int j = 0; j < 4; ++j)                                  \
            acc[4 + i][j] = __builtin_amdgcn_mfma_i32_16x16x64_i8(af2[i], bf[j], acc[4 + i][j], 0, 0, 0); \
    __builtin_amdgcn_s_setprio(0);                                                     \
    __builtin_amdgcn_s_barrier();                                                      \
  }

#define STAGE16(SRC, DST)                                                              \
  __builtin_amdgcn_global_load_lds(                                                    \
      (const __attribute__((address_space(1))) void*)(SRC),                            \
      (__attribute__((address_space(3))) void*)(DST), 16, 0, 0)

template <int WRITE_Q>
__global__ __launch_bounds__(512, 2) void gemm_kernel(
    const char* __restrict__ qa, const char* __restrict__ wb,
    const int* __restrict__ corr, const float* __restrict__ swp,
    const float* __restrict__ bias, const float* __restrict__ sp,
    const int* __restrict__ zpp, char* __restrict__ outq, float* __restrict__ outf) {
  __shared__ __align__(16) char lds[4][2][256 * 64];  // 128 KB
  const int tid = threadIdx.x;
  const int lane = tid & 63;
  const int w = tid >> 6;
  const int wr = w >> 2;   // 0..1 (M)
  const int wc = w & 3;    // 0..3 (N)
  const int bid = blockIdx.x;
  const int bm = bid & 31;  // M/256 = 32, fastest: neighbors share B panel
  const int bn = bid >> 5;  // N/256 = 16
  const char* abase = qa + (size_t)bm * 256 * K_DIM;
  const char* bbase = wb + (size_t)bn * 256 * K_DIM;

  // --- per-thread staging constants (inverse-swizzled global sources) ---
  const int o0_ = tid * 16;
  const int o1_ = 8192 + tid * 16;
  const int r0_ = o0_ >> 6, r1_ = o1_ >> 6;
  const int g0_ = ((o0_ >> 4) & 3) ^ ((r0_ >> 1) & 3);
  const int g1_ = ((o1_ >> 4) & 3) ^ ((r1_ >> 1) & 3);
  const char* asrc0 = abase + (size_t)r0_ * K_DIM + g0_ * 16;
  const char* asrc1 = abase + (size_t)r1_ * K_DIM + g1_ * 16;
  const char* bsrc0 = bbase + (size_t)r0_ * K_DIM + g0_ * 16;
  const char* bsrc1 = bbase + (size_t)r1_ * K_DIM + g1_ * 16;

  // --- per-thread ds_read byte offsets (swizzled) ---
  const int rr = lane & 15;
  const int g = lane >> 4;
  int aoff[8], boff[4];
#pragma unroll
  for (int i = 0; i < 8; ++i) {
    const int row = wr * 128 + i * 16 + rr;
    aoff[i] = (row << 6) + ((g ^ ((row >> 1) & 3)) << 4);
  }
#pragma unroll
  for (int j = 0; j < 4; ++j) {
    const int row = wc * 64 + j * 16 + rr;
    boff[j] = (row << 6) + ((g ^ ((row >> 1) & 3)) << 4);
  }

  i32x4 acc[8][4] = {};

  // --- prologue: stage tiles 0,1,2; wait tile 0 ---
  STAGE16(asrc0, &lds[0][0][o0_]); STAGE16(asrc1, &lds[0][0][o1_]);
  STAGE16(bsrc0, &lds[0][1][o0_]); STAGE16(bsrc1, &lds[0][1][o1_]);
  STAGE16(asrc0 + 64, &lds[1][0][o0_]); STAGE16(asrc1 + 64, &lds[1][0][o1_]);
  STAGE16(bsrc0 + 64, &lds[1][1][o0_]); STAGE16(bsrc1 + 64, &lds[1][1][o1_]);
  STAGE16(asrc0 + 128, &lds[2][0][o0_]); STAGE16(asrc1 + 128, &lds[2][0][o1_]);
  STAGE16(bsrc0 + 128, &lds[2][1][o0_]); STAGE16(bsrc1 + 128, &lds[2][1][o1_]);
  asm volatile("s_waitcnt vmcnt(8)" ::: "memory");
  __builtin_amdgcn_s_barrier();

  // --- main loop: tiles 0..KTILES-4 stage t+3, counted vmcnt(8) ---
  for (int t = 0; t < KTILES - 3; ++t) GEMM_TILE(t, true, VM8);
  // --- tail: drain 4 -> 0 -> none ---
  GEMM_TILE(KTILES - 3, false, VM4);
  GEMM_TILE(KTILES - 2, false, VM0);
  GEMM_TILE(KTILES - 1, false, VMN);

  // --- epilogue: C/D layout col = lane&15 (n), row = (lane>>4)*4 + reg (m) ---
  const float s = sp[0];
  const float zpf = (float)zpp[0];
  const int m0 = bm * 256 + wr * 128 + (lane >> 4) * 4;
  const int n0 = bn * 256 + wc * 64 + (lane & 15);
#pragma unroll
  for (int j = 0; j < 4; ++j) {
    const int n = n0 + j * 16;
    const int cr = corr[n];
    const float fs = s * swp[n];
    const float bb = bias[n];
#pragma unroll
    for (int i = 0; i < 8; ++i) {
#pragma unroll
      for (int q = 0; q < 4; ++q) {
        const int m = m0 + i * 16 + q;
        float val = fs * (float)(acc[i][j][q] + cr) + bb;
        if (WRITE_Q) {
          float tq = fminf(fmaxf(rintf(val / s) + zpf, 0.f), 255.f);
          outq[(size_t)m * N_DIM + n] = (char)((int)tq - 128);
        } else {
          outf[(size_t)m * N_DIM + n] = val;
        }
      }
    }
  }
}

// ---------------------------------------------------------------------------
extern "C" void kernel_launch(void* const* d_in, const int* in_sizes, int n_in,
                              void* d_out, int out_size, void* d_ws, size_t ws_size,
                              hipStream_t stream) {
  const float* x = (const float*)d_in[0];
  const int* wq = (const int*)d_in[1];
  const float* bias = (const float*)d_in[2];
  const float* s_in = (const float*)d_in[3];
  const int* zp_in = (const int*)d_in[4];
  const float* s_w = (const float*)d_in[5];
  float* out = (float*)d_out;

  const size_t WP_BYTES = (size_t)N_DIM * K_DIM;  // 16 MB packed int8 W
  const size_t Q_BYTES = (size_t)M_DIM * K_DIM;   // 32 MB int8 activations
  char* ws = (char*)d_ws;
  char* wp = ws;
  char* q1 = ws + WP_BYTES;
  char* q2 = q1 + Q_BYTES;
  int* corr = (int*)(q2 + Q_BYTES);
  const size_t NEEDED = WP_BYTES + 2 * Q_BYTES + (size_t)N_DIM * sizeof(int);
  if (ws_size < NEEDED) return;

  pack_w_kernel<<<N_DIM, 256, 0, stream>>>(wq, wp, corr, zp_in);
  quant_in_kernel<<<(M_DIM * K_DIM / 4) / 256, 256, 0, stream>>>(x, q1, s_in, zp_in);

  dim3 grid((M_DIM / 256) * (N_DIM / 256));  // 512 blocks
  dim3 blk(512);
  gemm_kernel<1><<<grid, blk, 0, stream>>>(q1, wp, corr, s_w, bias, s_in, zp_in, q2, nullptr);
  gemm_kernel<1><<<grid, blk, 0, stream>>>(q2, wp, corr, s_w, bias, s_in, zp_in, q1, nullptr);
  gemm_kernel<0><<<grid, blk, 0, stream>>>(q1, wp, corr, s_w, bias, s_in, zp_in, nullptr, out);
}

// Round 3
// 451.686 us; speedup vs baseline: 1.2415x; 1.0156x over previous
//
#include <hip/hip_runtime.h>
#include <stdint.h>

#define M_DIM 8192
#define K_DIM 4096
#define N_DIM 4096
#define KTILES (K_DIM / 64)

typedef __attribute__((ext_vector_type(4))) int i32x4;

// ---------------------------------------------------------------------------
// Pack int32-stored int8 weights [N,K] -> true int8 [N,K]; per-row sum folded
// into integer correction corr[n] = (128 - zp) * rowsum[n].
// ---------------------------------------------------------------------------
__global__ void pack_w_kernel(const int* __restrict__ w, char* __restrict__ wp,
                              int* __restrict__ corr, const int* __restrict__ zpp) {
  __shared__ int red[256];
  const int n = blockIdx.x;
  const int t = threadIdx.x;
  const int4* row = (const int4*)(w + (size_t)n * K_DIM);
  int s = 0;
  int words[4];
#pragma unroll
  for (int u = 0; u < 4; ++u) {
    int4 v = row[t * 4 + u];
    s += v.x + v.y + v.z + v.w;
    words[u] = (v.x & 255) | ((v.y & 255) << 8) | ((v.z & 255) << 16) | (v.w << 24);
  }
  ((int4*)(wp + (size_t)n * K_DIM))[t] = make_int4(words[0], words[1], words[2], words[3]);
  red[t] = s;
  __syncthreads();
  for (int off = 128; off > 0; off >>= 1) {
    if (t < off) red[t] += red[t + off];
    __syncthreads();
  }
  if (t == 0) corr[n] = (128 - zpp[0]) * red[0];
}

// ---------------------------------------------------------------------------
// Quantize fp32 input -> int8 (q - 128), 4 elements/thread.
// ---------------------------------------------------------------------------
__global__ void quant_in_kernel(const float* __restrict__ x, char* __restrict__ q,
                                const float* __restrict__ sp, const int* __restrict__ zpp) {
  const int i = blockIdx.x * blockDim.x + threadIdx.x;
  const float s = sp[0];
  const float zp = (float)zpp[0];
  float4 v = ((const float4*)x)[i];
  float t0 = fminf(fmaxf(rintf(v.x / s) + zp, 0.f), 255.f);
  float t1 = fminf(fmaxf(rintf(v.y / s) + zp, 0.f), 255.f);
  float t2 = fminf(fmaxf(rintf(v.z / s) + zp, 0.f), 255.f);
  float t3 = fminf(fmaxf(rintf(v.w / s) + zp, 0.f), 255.f);
  int b0 = (int)t0 - 128, b1 = (int)t1 - 128, b2 = (int)t2 - 128, b3 = (int)t3 - 128;
  ((int*)q)[i] = (b0 & 255) | ((b1 & 255) << 8) | ((b2 & 255) << 16) | (b3 << 24);
}

// ---------------------------------------------------------------------------
// 256x256 i8 GEMM, software-pipelined registers, ONE barrier per K-tile.
// A = qa [M,K] int8 (q-128), B = wb [N,K] int8, out = fs[n]*(dot+corr[n])+b[n].
// 512 threads = 8 waves (2M x 4N), per-wave 128x64 out, BK=64 bytes.
// LDS: 4-slot ring (A 16KB + B 16KB per slot) = 128 KB, prefetch distance 3.
// Pipeline invariant at tile-t start: slots t and t+1 staging-CONFIRMED
// (vmcnt(4) at each tile end confirms slot t+2), slot t+2 in flight.
// Per tile: [read P1 frags(slot t)] [stage A(t+3)] [MFMA P0] [read next-tile
// P0 frags(slot t+1)] [stage B(t+3)] [MFMA P1] [vmcnt(4)] [barrier].
// All ds_reads are plain C++ loads -> compiler emits counted lgkmcnt before
// each consuming MFMA; reads of a slot always retire before the barrier that
// precedes its overwrite (stage during t hits slot t-1, fully read).
// Swizzle (verified 0 conflicts): 16B slot g_phys = g ^ ((row>>1)&3), applied
// to global source at staging and to ds_read addr.
// ---------------------------------------------------------------------------
#define STAGE16(SRC, DST)                                                     \
  __builtin_amdgcn_global_load_lds(                                           \
      (const __attribute__((address_space(1))) void*)(SRC),                   \
      (__attribute__((address_space(3))) void*)(DST), 16, 0, 0)

#define RD(p) (*(const i32x4*)(p))

#define TILE(SLOT, KSTG, DO_NEXT)                                             \
  {                                                                           \
    const char* bufA_ = &lds[SLOT][0][0];                                     \
    char* nA_ = &lds[((SLOT) + 3) & 3][0][0];                                 \
    char* nB_ = &lds[((SLOT) + 3) & 3][1][0];                                 \
    i32x4 a1_[4];                                                             \
    _Pragma("unroll") for (int i_ = 0; i_ < 4; ++i_)                          \
        a1_[i_] = RD(bufA_ + aoff[4 + i_]);                                   \
    STAGE16(asrc0 + (size_t)(KSTG) * 64, nA_ + o0_);                          \
    STAGE16(asrc1 + (size_t)(KSTG) * 64, nA_ + o1_);                          \
    __builtin_amdgcn_s_setprio(1);                                            \
    _Pragma("unroll") for (int i_ = 0; i_ < 4; ++i_)                          \
        _Pragma("unroll") for (int j_ = 0; j_ < 4; ++j_)                      \
            acc[i_][j_] = __builtin_amdgcn_mfma_i32_16x16x64_i8(              \
                a0[i_], b0[j_], acc[i_][j_], 0, 0, 0);                        \
    __builtin_amdgcn_s_setprio(0);                                            \
    i32x4 ta_[4], tb_[4];                                                     \
    if (DO_NEXT) {                                                            \
      const char* xA_ = &lds[((SLOT) + 1) & 3][0][0];                         \
      const char* xB_ = &lds[((SLOT) + 1) & 3][1][0];                         \
      _Pragma("unroll") for (int i_ = 0; i_ < 4; ++i_)                        \
          ta_[i_] = RD(xA_ + aoff[i_]);                                       \
      _Pragma("unroll") for (int j_ = 0; j_ < 4; ++j_)                        \
          tb_[j_] = RD(xB_ + boff[j_]);                                       \
    }                                                                         \
    STAGE16(bsrc0 + (size_t)(KSTG) * 64, nB_ + o0_);                          \
    STAGE16(bsrc1 + (size_t)(KSTG) * 64, nB_ + o1_);                          \
    __builtin_amdgcn_s_setprio(1);                                            \
    _Pragma("unroll") for (int i_ = 0; i_ < 4; ++i_)                          \
        _Pragma("unroll") for (int j_ = 0; j_ < 4; ++j_)                      \
            acc[4 + i_][j_] = __builtin_amdgcn_mfma_i32_16x16x64_i8(          \
                a1_[i_], b0[j_], acc[4 + i_][j_], 0, 0, 0);                   \
    __builtin_amdgcn_s_setprio(0);                                            \
    asm volatile("s_waitcnt vmcnt(4)" ::: "memory");                          \
    __builtin_amdgcn_s_barrier();                                             \
    if (DO_NEXT) {                                                            \
      _Pragma("unroll") for (int i_ = 0; i_ < 4; ++i_) a0[i_] = ta_[i_];      \
      _Pragma("unroll") for (int j_ = 0; j_ < 4; ++j_) b0[j_] = tb_[j_];      \
    }                                                                         \
  }

template <int WRITE_Q>
__global__ __launch_bounds__(512, 2) void gemm_kernel(
    const char* __restrict__ qa, const char* __restrict__ wb,
    const int* __restrict__ corr, const float* __restrict__ swp,
    const float* __restrict__ bias, const float* __restrict__ sp,
    const int* __restrict__ zpp, char* __restrict__ outq, float* __restrict__ outf) {
  __shared__ __align__(16) char lds[4][2][16384];  // 128 KB: 4-slot ring
  const int tid = threadIdx.x;
  const int lane = tid & 63;
  const int w = tid >> 6;
  const int wr = w >> 2;   // 0..1 (M)
  const int wc = w & 3;    // 0..3 (N)
  const int bid = blockIdx.x;
  const int bm = bid & 31;  // M/256 = 32, fastest: neighbors share B panel
  const int bn = bid >> 5;  // N/256 = 16
  const char* abase = qa + (size_t)bm * 256 * K_DIM;
  const char* bbase = wb + (size_t)bn * 256 * K_DIM;

  // --- per-thread staging constants (inverse-swizzled global sources) ---
  const int o0_ = tid * 16;
  const int o1_ = 8192 + tid * 16;
  const int r0_ = o0_ >> 6, r1_ = o1_ >> 6;
  const int g0_ = ((o0_ >> 4) & 3) ^ ((r0_ >> 1) & 3);
  const int g1_ = ((o1_ >> 4) & 3) ^ ((r1_ >> 1) & 3);
  const char* asrc0 = abase + (size_t)r0_ * K_DIM + g0_ * 16;
  const char* asrc1 = abase + (size_t)r1_ * K_DIM + g1_ * 16;
  const char* bsrc0 = bbase + (size_t)r0_ * K_DIM + g0_ * 16;
  const char* bsrc1 = bbase + (size_t)r1_ * K_DIM + g1_ * 16;

  // --- per-thread ds_read byte offsets (swizzled) ---
  const int rr = lane & 15;
  const int g = lane >> 4;
  int aoff[8], boff[4];
#pragma unroll
  for (int i = 0; i < 8; ++i) {
    const int row = wr * 128 + i * 16 + rr;
    aoff[i] = (row << 6) + ((g ^ ((row >> 1) & 3)) << 4);
  }
#pragma unroll
  for (int j = 0; j < 4; ++j) {
    const int row = wc * 64 + j * 16 + rr;
    boff[j] = (row << 6) + ((g ^ ((row >> 1) & 3)) << 4);
  }

  i32x4 acc[8][4] = {};

  // --- prologue: stage slots 0,1,2 (tiles 0,1,2); confirm slots 0 AND 1 ---
  STAGE16(asrc0, &lds[0][0][o0_]); STAGE16(asrc1, &lds[0][0][o1_]);
  STAGE16(bsrc0, &lds[0][1][o0_]); STAGE16(bsrc1, &lds[0][1][o1_]);
  STAGE16(asrc0 + 64, &lds[1][0][o0_]); STAGE16(asrc1 + 64, &lds[1][0][o1_]);
  STAGE16(bsrc0 + 64, &lds[1][1][o0_]); STAGE16(bsrc1 + 64, &lds[1][1][o1_]);
  STAGE16(asrc0 + 128, &lds[2][0][o0_]); STAGE16(asrc1 + 128, &lds[2][0][o1_]);
  STAGE16(bsrc0 + 128, &lds[2][1][o0_]); STAGE16(bsrc1 + 128, &lds[2][1][o1_]);
  asm volatile("s_waitcnt vmcnt(4)" ::: "memory");  // slots 0,1 confirmed
  __builtin_amdgcn_s_barrier();

  i32x4 a0[4], b0[4];
#pragma unroll
  for (int i = 0; i < 4; ++i) a0[i] = RD(&lds[0][0][0] + aoff[i]);
#pragma unroll
  for (int j = 0; j < 4; ++j) b0[j] = RD(&lds[0][1][0] + boff[j]);

  // --- main loop: t = 0..59 (slots cycle 0..3) ---
  for (int tb = 0; tb < (KTILES - 4) / 4; ++tb) {
    const int t0 = tb * 4;
#pragma unroll
    for (int u = 0; u < 4; ++u) {
      TILE(u, t0 + u + 3, 1);
    }
  }
  // --- peeled tail: t = 60,61,62,63; stage kt clamps to 63 (re-stage) ---
  TILE(0, KTILES - 1, 1);
  TILE(1, KTILES - 1, 1);
  TILE(2, KTILES - 1, 1);
  TILE(3, KTILES - 1, 0);
  asm volatile("s_waitcnt vmcnt(0)" ::: "memory");  // drain before exit

  // --- epilogue: C/D layout col = lane&15 (n), row = (lane>>4)*4 + reg (m) ---
  const float s = sp[0];
  const float zpf = (float)zpp[0];
  const int m0 = bm * 256 + wr * 128 + (lane >> 4) * 4;
  const int n0 = bn * 256 + wc * 64 + (lane & 15);
#pragma unroll
  for (int j = 0; j < 4; ++j) {
    const int n = n0 + j * 16;
    const int cr = corr[n];
    const float fs = s * swp[n];
    const float bb = bias[n];
#pragma unroll
    for (int i = 0; i < 8; ++i) {
#pragma unroll
      for (int q = 0; q < 4; ++q) {
        const int m = m0 + i * 16 + q;
        float val = fs * (float)(acc[i][j][q] + cr) + bb;
        if (WRITE_Q) {
          float tq = fminf(fmaxf(rintf(val / s) + zpf, 0.f), 255.f);
          outq[(size_t)m * N_DIM + n] = (char)((int)tq - 128);
        } else {
          outf[(size_t)m * N_DIM + n] = val;
        }
      }
    }
  }
}

// ---------------------------------------------------------------------------
extern "C" void kernel_launch(void* const* d_in, const int* in_sizes, int n_in,
                              void* d_out, int out_size, void* d_ws, size_t ws_size,
                              hipStream_t stream) {
  const float* x = (const float*)d_in[0];
  const int* wq = (const int*)d_in[1];
  const float* bias = (const float*)d_in[2];
  const float* s_in = (const float*)d_in[3];
  const int* zp_in = (const int*)d_in[4];
  const float* s_w = (const float*)d_in[5];
  float* out = (float*)d_out;

  const size_t WP_BYTES = (size_t)N_DIM * K_DIM;  // 16 MB packed int8 W
  const size_t Q_BYTES = (size_t)M_DIM * K_DIM;   // 32 MB int8 activations
  char* ws = (char*)d_ws;
  char* wp = ws;
  char* q1 = ws + WP_BYTES;
  char* q2 = q1 + Q_BYTES;
  int* corr = (int*)(q2 + Q_BYTES);
  const size_t NEEDED = WP_BYTES + 2 * Q_BYTES + (size_t)N_DIM * sizeof(int);
  if (ws_size < NEEDED) return;

  pack_w_kernel<<<N_DIM, 256, 0, stream>>>(wq, wp, corr, zp_in);
  quant_in_kernel<<<(M_DIM * K_DIM / 4) / 256, 256, 0, stream>>>(x, q1, s_in, zp_in);

  dim3 grid((M_DIM / 256) * (N_DIM / 256));  // 512 blocks
  dim3 blk(512);
  gemm_kernel<1><<<grid, blk, 0, stream>>>(q1, wp, corr, s_w, bias, s_in, zp_in, q2, nullptr);
  gemm_kernel<1><<<grid, blk, 0, stream>>>(q2, wp, corr, s_w, bias, s_in, zp_in, q1, nullptr);
  gemm_kernel<0><<<grid, blk, 0, stream>>>(q1, wp, corr, s_w, bias, s_in, zp_in, nullptr, out);
}